// Round 5
// baseline (614.499 us; speedup 1.0000x reference)
//
#include <hip/hip_runtime.h>
#include <hip/hip_bf16.h>
#include <math.h>

#define NN 50000
#define IN_DIM 1024
#define EE 100000
#define NUM_REL 40
#define HEADS 4
#define OUT_D 200
#define HID 800
#define BB 8192
#define SLOT_CAP 16384
#define SRC_CAP 50176   // max rows in xg (>= NN rounded to tile)
#define WT_COLS 1024    // Wt padded to 1024 cols (800 W + 8 Wa + zeros)

typedef __attribute__((ext_vector_type(8))) short short8;
typedef __attribute__((ext_vector_type(4))) float f32x4;

__device__ inline unsigned short f2bf(float f) {
    unsigned int u = __float_as_uint(f);
    u += 0x7FFF + ((u >> 16) & 1);
    return (unsigned short)(u >> 16);
}
__device__ inline float bf2f(unsigned short s) {
    return __uint_as_float(((unsigned int)s) << 16);
}
__device__ inline void gl2lds16(const unsigned short* g, unsigned short* l) {
    __builtin_amdgcn_global_load_lds(
        (const __attribute__((address_space(1))) void*)g,
        (__attribute__((address_space(3))) void*)l, 16, 0, 0);
}

// ---------------- init ----------------
__global__ void k_init(int* slot_of_node, int* xrow_of_node, int* deg, int* counters) {
    int i = blockIdx.x * 256 + threadIdx.x;
    if (i < NN) { slot_of_node[i] = -1; xrow_of_node[i] = -1; }
    if (i < SLOT_CAP) deg[i] = 0;
    if (i < 8) counters[i] = 0;
}

// compact score nodes (src_ids ∪ dst_ids) -> slots; record unique score list
__global__ void k_build_slots(const int* src_ids, const int* dst_ids,
                              int* slot_of_node, int* counters, int* scorelist) {
    int i = blockIdx.x * 256 + threadIdx.x;
    if (i >= 2 * BB) return;
    int n = (i < BB) ? src_ids[i] : dst_ids[i - BB];
    if (slot_of_node[n] == -1) {
        if (atomicCAS(&slot_of_node[n], -1, -2) == -1) {
            int s = atomicAdd(&counters[0], 1);
            slot_of_node[n] = s;
            scorelist[s] = n;
        }
    }
}

// Wa[k][c] (8192 outputs) and prel[r][h] (160 outputs): one WAVE per output.
// lane covers d = 4*lane (<200) with a single float4; shuffle-reduce.
__global__ __launch_bounds__(256) void k_wa(const float* W, const float* a_src,
                                            const float* a_dst, const float* a_rel,
                                            const float* rel_feat, float* Wa, float* prel) {
    int wid = blockIdx.x * 4 + (threadIdx.x >> 6);
    int lane = threadIdx.x & 63;
    if (wid >= IN_DIM * 8 + NUM_REL * HEADS) return;
    float acc = 0.f;
    int d = lane * 4;
    if (d < OUT_D) {
        const float* row;
        const float* a;
        if (wid < IN_DIM * 8) {
            int k = wid >> 3, c = wid & 7;
            int h = c & 3;
            row = W + (size_t)k * HID + h * OUT_D;
            a = ((c < 4) ? a_src : a_dst) + h * OUT_D;
        } else {
            int j = wid - IN_DIM * 8;
            int r = j >> 2, h = j & 3;
            row = rel_feat + (size_t)r * HID + h * OUT_D;
            a = a_rel + h * OUT_D;
        }
        float4 wv = *(const float4*)(row + d);
        float4 av = *(const float4*)(a + d);
        acc = wv.x * av.x + wv.y * av.y + wv.z * av.z + wv.w * av.w;
    }
    for (int off = 32; off; off >>= 1) acc += __shfl_down(acc, off, 64);
    if (lane == 0) {
        if (wid < IN_DIM * 8) Wa[wid] = acc;
        else prel[wid - IN_DIM * 8] = acc;
    }
}

// survivor pass: compact srcs of surviving edges (xrows 0..nsrc), per-slot degree
__global__ void k_edge0(const int* ei, const int* slot_of_node,
                        int* xrow_of_node, int* counters, int* rows, int* deg) {
    int e = blockIdx.x * 256 + threadIdx.x;
    if (e >= EE) return;
    int dn = ei[EE + e];
    int slot = slot_of_node[dn];
    if (slot < 0) return;
    int sn = ei[e];
    if (xrow_of_node[sn] == -1) {
        if (atomicCAS(&xrow_of_node[sn], -1, -2) == -1) {
            int t = atomicAdd(&counters[1], 1);
            rows[t] = sn;
            xrow_of_node[sn] = t;
        }
    }
    atomicAdd(&deg[slot], 1);
}

// append score nodes that aren't srcs as tail xrows (nsrc..nneed)
__global__ void k_tail(const int* scorelist, int* xrow_of_node, int* counters, int* rows) {
    int i = blockIdx.x * 256 + threadIdx.x;
    if (i >= counters[0]) return;
    int n = scorelist[i];
    if (xrow_of_node[n] < 0) {
        int t = atomicAdd(&counters[3], 1);
        int xr = counters[1] + t;   // counters[1] stable: edge0 completed
        xrow_of_node[n] = xr;
        rows[xr] = n;
    }
}

// exclusive prefix sum over deg[SLOT_CAP] -> base, cursor (single block, int4 loads)
__global__ __launch_bounds__(256) void k_scan(const int* deg, int* base, int* cursor) {
    __shared__ int pref[257];
    int t = threadIdx.x;
    int s = 0;
    const int4* dv = (const int4*)(deg + t * (SLOT_CAP / 256));
    for (int i = 0; i < SLOT_CAP / 256 / 4; ++i) {
        int4 v = dv[i];
        s += v.x + v.y + v.z + v.w;
    }
    pref[t + 1] = s;
    if (t == 0) pref[0] = 0;
    __syncthreads();
    if (t == 0)
        for (int i = 1; i <= 256; ++i) pref[i] += pref[i - 1];
    __syncthreads();
    int r = pref[t];
    for (int i = 0; i < SLOT_CAP / 256; ++i) {
        int idx = t * (SLOT_CAP / 256) + i;
        base[idx] = r;
        cursor[idx] = r;
        r += deg[idx];
    }
}

// gather + cast: xg[xr][k] = bf16(x[rows[xr]][k]); no LDS
__global__ __launch_bounds__(256) void k_gather_cast(const float* x, const int* rows,
                                                     const int* counters, unsigned short* xg) {
    int nneed = counters[1] + counters[3];
    int gid = blockIdx.x * 256 + threadIdx.x;
    int row = gid >> 7;            // 128 threads per row, 8 elems each
    if (row >= nneed) return;
    int j = (gid & 127) * 8;
    int node = rows[row];
    const float* src = x + (size_t)node * IN_DIM + j;
    float4 a = *(const float4*)(src);
    float4 b = *(const float4*)(src + 4);
    unsigned short o[8] = {f2bf(a.x), f2bf(a.y), f2bf(a.z), f2bf(a.w),
                           f2bf(b.x), f2bf(b.y), f2bf(b.z), f2bf(b.w)};
    *(short8*)(xg + (size_t)row * IN_DIM + j) = *(short8*)o;
}

// transpose+cast W -> Wt[1024][1024] bf16; cols 800..807 = Wa, 808..1023 = 0
__global__ __launch_bounds__(256) void k_wt(const float* W, const float* Wa,
                                            unsigned short* Wt) {
    __shared__ float tile[64][65];
    int k0 = blockIdx.x * 64, c0 = blockIdx.y * 64;
    int t = threadIdx.x;
    {
        int kk = t >> 2, cc = (t & 3) * 16;
        for (int i = 0; i < 16; ++i) {
            int c = c0 + cc + i;
            float v = 0.f;
            if (c < HID) v = W[(size_t)(k0 + kk) * HID + c];
            else if (c < HID + 8) v = Wa[(size_t)(k0 + kk) * 8 + (c - HID)];
            tile[cc + i][kk] = v;
        }
    }
    __syncthreads();
    {
        int cc = t >> 2, kk = (t & 3) * 16;
        unsigned short o[16];
        for (int i = 0; i < 16; ++i) o[i] = f2bf(tile[cc][kk + i]);
        *(short8*)(Wt + (size_t)(c0 + cc) * IN_DIM + k0 + kk) = *(short8*)o;
        *(short8*)(Wt + (size_t)(c0 + cc) * IN_DIM + k0 + kk + 8) = *(short8*)(o + 8);
    }
}

// MFMA bf16 GEMM, 128x256 tile (4 col-tiles over 1024 padded cols) to halve
// A-refetch. global_load_lds(16B) into fragment-ordered LDS (conflict-free).
// Col-tiles 0..2: rows < nsrc. Col-tile 3 (768..1023): rows < nneed, cols
// 800..807 routed to fp32 sS/sD.
#define GBM 128
#define GBN 256
#define GBK 32
__global__ __launch_bounds__(256) void k_hgemm(const unsigned short* xg, const unsigned short* Wt,
                                               const int* counters, unsigned short* h_src,
                                               float* sS, float* sD) {
    int nsrc = counters[1];
    int nneed = nsrc + counters[3];
    int col0 = blockIdx.x * GBN;
    int row0 = blockIdx.y * GBM;
    int rowlim = (col0 == 768) ? nneed : nsrc;
    if (row0 >= rowlim) return;
    __shared__ unsigned short As[GBM * GBK];  // 8 KB
    __shared__ unsigned short Bs[GBN * GBK];  // 16 KB
    int t = threadIdx.x;
    // chunk c (16B): row (c>>6)*16 + (c&15), k-offset ((c>>4)&3)*8
    int crow = ((t >> 6) << 4) + (t & 15), coff = ((t >> 4) & 3) << 3;
    const unsigned short* a0 = xg + (size_t)(row0 + crow) * IN_DIM + coff;
    const unsigned short* a1 = a0 + (size_t)64 * IN_DIM;
    const unsigned short* b0 = Wt + (size_t)(col0 + crow) * IN_DIM + coff;
    const unsigned short* b1 = b0 + (size_t)64 * IN_DIM;
    const unsigned short* b2 = b0 + (size_t)128 * IN_DIM;
    const unsigned short* b3 = b0 + (size_t)192 * IN_DIM;
    unsigned short* la0 = As + t * 8;
    unsigned short* la1 = As + (256 + t) * 8;
    unsigned short* lb0 = Bs + t * 8;
    unsigned short* lb1 = Bs + (256 + t) * 8;
    unsigned short* lb2 = Bs + (512 + t) * 8;
    unsigned short* lb3 = Bs + (768 + t) * 8;
    int w = t >> 6, lane = t & 63;
    int ga = (w >> 1) * 4, gb = (w & 1) * 8;
    int wr = (w >> 1) * 64, wc = (w & 1) * 128;
    int fm = lane & 15, fq = lane >> 4;
    f32x4 acc[4][8] = {};
    for (int k0 = 0; k0 < IN_DIM; k0 += GBK) {
        __syncthreads();
        gl2lds16(a0 + k0, la0);
        gl2lds16(a1 + k0, la1);
        gl2lds16(b0 + k0, lb0);
        gl2lds16(b1 + k0, lb1);
        gl2lds16(b2 + k0, lb2);
        gl2lds16(b3 + k0, lb3);
        __syncthreads();
        short8 af[4], bf[8];
#pragma unroll
        for (int i = 0; i < 4; ++i)
            af[i] = *(const short8*)&As[((ga + i) * 64 + lane) * 8];
#pragma unroll
        for (int j = 0; j < 8; ++j)
            bf[j] = *(const short8*)&Bs[((gb + j) * 64 + lane) * 8];
#pragma unroll
        for (int i = 0; i < 4; ++i)
#pragma unroll
            for (int j = 0; j < 8; ++j)
                acc[i][j] = __builtin_amdgcn_mfma_f32_16x16x32_bf16(af[i], bf[j], acc[i][j], 0, 0, 0);
    }
#pragma unroll
    for (int i = 0; i < 4; ++i) {
#pragma unroll
        for (int j = 0; j < 8; ++j) {
            int gcol = col0 + wc + j * 16 + fm;
            if (gcol >= HID + 8) continue;
#pragma unroll
            for (int r = 0; r < 4; ++r) {
                int grow = row0 + wr + i * 16 + fq * 4 + r;
                float v = acc[i][j][r];
                if (gcol < HID) {
                    if (grow < nsrc) h_src[(size_t)grow * HID + gcol] = f2bf(v);
                } else if (grow < nneed) {
                    int c = gcol - HID;
                    if (c < 4) sS[grow * 4 + c] = v;
                    else sD[grow * 4 + (c - 4)] = v;
                }
            }
        }
    }
}

// place surviving edges into CSR, computing logits at final position
__global__ void k_place(const int* ei, const int* etype, const int* slot_of_node,
                        const int* xrow_of_node, int* cursor,
                        const float* sS, const float* sD, const float* prel,
                        float* clogit, int* tlist) {
    int e = blockIdx.x * 256 + threadIdx.x;
    if (e >= EE) return;
    int dn = ei[EE + e];
    int slot = slot_of_node[dn];
    if (slot < 0) return;
    int sn = ei[e];
    int r = etype[e];
    int xs = xrow_of_node[sn];
    int xd = xrow_of_node[dn];
    int pos = atomicAdd(&cursor[slot], 1);
    tlist[pos] = xs;
    float4 lg;
    float* lp = (float*)&lg;
#pragma unroll
    for (int h = 0; h < 4; ++h) {
        float v = sS[xs * 4 + h] + sD[xd * 4 + h] + prel[r * 4 + h];
        lp[h] = v > 0.f ? v : 0.2f * v;
    }
    *(float4*)&clogit[(size_t)pos * 4] = lg;
}

// per-dst-slot softmax + aggregate (no atomics): one block per slot
__global__ __launch_bounds__(256) void k_aggregate(const int* counters, const int* base,
                                                   const int* deg, const int* tlist,
                                                   const float* clogit,
                                                   const unsigned short* h_src, const float* bias,
                                                   float* refined) {
    int b = blockIdx.x;
    if (b >= counters[0]) return;
    int beg = base[b], d = deg[b];
    __shared__ float m4[4], den4[4];
    __shared__ float alpha[64][4];
    __shared__ int tsl[64];
    int t = threadIdx.x;
    if (t < 4) {
        float m = -3e38f;
        for (int j = 0; j < d; ++j)
            m = fmaxf(m, clogit[(size_t)(beg + j) * 4 + t]);
        float s = 0.f;
        for (int j = 0; j < d; ++j)
            s += expf(clogit[(size_t)(beg + j) * 4 + t] - m);
        m4[t] = m;
        den4[t] = s;
    }
    __syncthreads();
    int h0 = t / 200, h1 = (t + 256) / 200, h2 = (t + 512) / 200;
    float acc0 = 0.f, acc1 = 0.f, acc2 = 0.f, acc3 = 0.f;
    for (int j0 = 0; j0 < d; j0 += 64) {
        int nc = min(64, d - j0);
        if (t < nc * 4) {
            int j = t >> 2, h = t & 3;
            alpha[j][h] = expf(clogit[(size_t)(beg + j0 + j) * 4 + h] - m4[h]) / den4[h];
            if (h == 0) tsl[j] = tlist[beg + j0 + j];
        }
        __syncthreads();
        for (int j = 0; j < nc; ++j) {
            const unsigned short* hr = h_src + (size_t)tsl[j] * HID;
            acc0 += alpha[j][h0] * bf2f(hr[t]);
            acc1 += alpha[j][h1] * bf2f(hr[t + 256]);
            acc2 += alpha[j][h2] * bf2f(hr[t + 512]);
            if (t < 32) acc3 += alpha[j][3] * bf2f(hr[768 + t]);
        }
        __syncthreads();
    }
    float* rr = refined + (size_t)b * HID;
    rr[t] = acc0 + bias[t];
    rr[t + 256] = acc1 + bias[t + 256];
    rr[t + 512] = acc2 + bias[t + 512];
    if (t < 32) rr[768 + t] = acc3 + bias[768 + t];
}

// DistMult scoring: one wave per triple, float4 loads
__global__ __launch_bounds__(256) void k_score(const int* src_ids, const int* rel_ids,
                                               const int* dst_ids, const int* slot_of_node,
                                               const float* rel_emb, const float* refined,
                                               float* out) {
    int gid = blockIdx.x * 256 + threadIdx.x;
    int b = gid >> 6;
    int lane = threadIdx.x & 63;
    if (b >= BB) return;
    int ss = slot_of_node[src_ids[b]];
    int ds = slot_of_node[dst_ids[b]];
    int r = rel_ids[b];
    const float* sv = refined + (size_t)ss * HID;
    const float* dv = refined + (size_t)ds * HID;
    const float* rv = rel_emb + (size_t)r * HID;
    float acc = 0.f;
    for (int c4 = lane; c4 < 200; c4 += 64) {
        float4 s = *(const float4*)(sv + c4 * 4);
        float4 dq = *(const float4*)(dv + c4 * 4);
        float4 rr = *(const float4*)(rv + c4 * 4);
        acc += s.x * rr.x * dq.x + s.y * rr.y * dq.y + s.z * rr.z * dq.z + s.w * rr.w * dq.w;
    }
    for (int off = 32; off; off >>= 1) acc += __shfl_down(acc, off, 64);
    if (lane == 0) out[b] = acc;
}

extern "C" void kernel_launch(void* const* d_in, const int* in_sizes, int n_in,
                              void* d_out, int out_size, void* d_ws, size_t ws_size,
                              hipStream_t stream) {
    const float* node_emb = (const float*)d_in[0];
    const float* W        = (const float*)d_in[1];
    const float* bias     = (const float*)d_in[2];
    const float* a_src    = (const float*)d_in[3];
    const float* a_dst    = (const float*)d_in[4];
    const float* a_rel    = (const float*)d_in[5];
    const float* rel_feat = (const float*)d_in[6];
    const float* rel_emb  = (const float*)d_in[7];
    const int* edge_index = (const int*)d_in[8];
    const int* edge_type  = (const int*)d_in[9];
    const int* src_ids    = (const int*)d_in[10];
    const int* rel_ids    = (const int*)d_in[11];
    const int* dst_ids    = (const int*)d_in[12];
    float* out = (float*)d_out;

    char* w = (char*)d_ws;
    auto alloc = [&](size_t bytes) -> void* {
        void* p = (void*)w;
        w += (bytes + 255) & ~(size_t)255;
        return p;
    };
    int* slot_of_node = (int*)alloc((size_t)NN * 4);
    int* xrow_of_node = (int*)alloc((size_t)NN * 4);
    int* scorelist    = (int*)alloc((size_t)SLOT_CAP * 4);
    int* rows         = (int*)alloc((size_t)NN * 4);
    int* counters     = (int*)alloc(256);
    int* deg          = (int*)alloc((size_t)SLOT_CAP * 4);
    int* base         = (int*)alloc((size_t)SLOT_CAP * 4);
    int* cursor       = (int*)alloc((size_t)SLOT_CAP * 4);
    int* tlist        = (int*)alloc((size_t)EE * 4);
    float* clogit = (float*)alloc((size_t)EE * 4 * 4);
    float* sS     = (float*)alloc((size_t)SRC_CAP * 4 * 4);
    float* sD     = (float*)alloc((size_t)SRC_CAP * 4 * 4);
    float* Wa     = (float*)alloc((size_t)IN_DIM * 8 * 4);
    float* prel   = (float*)alloc((size_t)NUM_REL * 4 * 4);
    unsigned short* xg    = (unsigned short*)alloc((size_t)SRC_CAP * IN_DIM * 2);
    unsigned short* Wt    = (unsigned short*)alloc((size_t)WT_COLS * IN_DIM * 2);
    unsigned short* h_src = (unsigned short*)alloc((size_t)SRC_CAP * HID * 2);
    float* refined = (float*)alloc((size_t)SLOT_CAP * HID * 4);

    k_init<<<256, 256, 0, stream>>>(slot_of_node, xrow_of_node, deg, counters);
    k_build_slots<<<(2 * BB + 255) / 256, 256, 0, stream>>>(src_ids, dst_ids, slot_of_node,
                                                            counters, scorelist);
    k_wa<<<(IN_DIM * 8 + NUM_REL * HEADS + 3) / 4, 256, 0, stream>>>(
        W, a_src, a_dst, a_rel, rel_feat, Wa, prel);
    k_edge0<<<(EE + 255) / 256, 256, 0, stream>>>(edge_index, slot_of_node,
                                                  xrow_of_node, counters, rows, deg);
    k_tail<<<(SLOT_CAP + 255) / 256, 256, 0, stream>>>(scorelist, xrow_of_node, counters, rows);
    k_scan<<<1, 256, 0, stream>>>(deg, base, cursor);
    k_gather_cast<<<(NN * 128 + 255) / 256, 256, 0, stream>>>(node_emb, rows, counters, xg);
    k_wt<<<dim3(IN_DIM / 64, WT_COLS / 64), 256, 0, stream>>>(W, Wa, Wt);
    dim3 ggrid(WT_COLS / GBN, (SRC_CAP + GBM - 1) / GBM);
    k_hgemm<<<ggrid, 256, 0, stream>>>(xg, Wt, counters, h_src, sS, sD);
    k_place<<<(EE + 255) / 256, 256, 0, stream>>>(edge_index, edge_type, slot_of_node,
                                                  xrow_of_node, cursor, sS, sD, prel,
                                                  clogit, tlist);
    k_aggregate<<<SLOT_CAP, 256, 0, stream>>>(counters, base, deg, tlist,
                                              clogit, h_src, bias, refined);
    k_score<<<(BB * 64 + 255) / 256, 256, 0, stream>>>(src_ids, rel_ids, dst_ids,
                                                       slot_of_node, rel_emb, refined, out);
}

// Round 6
// 515.267 us; speedup vs baseline: 1.1926x; 1.1926x over previous
//
#include <hip/hip_runtime.h>
#include <hip/hip_bf16.h>
#include <math.h>

#define NN 50000
#define IN_DIM 1024
#define EE 100000
#define NUM_REL 40
#define HEADS 4
#define OUT_D 200
#define HID 800
#define BB 8192
#define SLOT_CAP 16384
#define SRC_CAP 50176   // max rows in xg (>= NN rounded to tile)
#define WT_COLS 896     // 800 W cols + 8 Wa cols + pad

typedef __attribute__((ext_vector_type(8))) short short8;
typedef __attribute__((ext_vector_type(4))) float f32x4;

__device__ inline unsigned short f2bf(float f) {
    unsigned int u = __float_as_uint(f);
    u += 0x7FFF + ((u >> 16) & 1);
    return (unsigned short)(u >> 16);
}
__device__ inline float bf2f(unsigned short s) {
    return __uint_as_float(((unsigned int)s) << 16);
}
__device__ inline void gl2lds16(const unsigned short* g, unsigned short* l) {
    __builtin_amdgcn_global_load_lds(
        (const __attribute__((address_space(1))) void*)g,
        (__attribute__((address_space(3))) void*)l, 16, 0, 0);
}

// ---------------- fused: init (blocks 0..195) | Wa/prel (blocks 196..) ----------------
#define INIT_BLOCKS 196
__global__ __launch_bounds__(256) void k_init_wa(int* slot_of_node, int* xrow_of_node,
                                                 int* deg, int* counters,
                                                 const float* W, const float* a_src,
                                                 const float* a_dst, const float* a_rel,
                                                 const float* rel_feat, float* Wa, float* prel) {
    int b = blockIdx.x;
    if (b < INIT_BLOCKS) {
        int i = b * 256 + threadIdx.x;
        if (i < NN) { slot_of_node[i] = -1; xrow_of_node[i] = -1; }
        if (i < SLOT_CAP) deg[i] = 0;
        if (i < 8) counters[i] = 0;
        return;
    }
    // one WAVE per output; lane covers d = 4*lane (<200) with one float4
    int wid = (b - INIT_BLOCKS) * 4 + (threadIdx.x >> 6);
    int lane = threadIdx.x & 63;
    if (wid >= IN_DIM * 8 + NUM_REL * HEADS) return;
    float acc = 0.f;
    int d = lane * 4;
    if (d < OUT_D) {
        const float* row;
        const float* a;
        if (wid < IN_DIM * 8) {
            int k = wid >> 3, c = wid & 7;
            int h = c & 3;
            row = W + (size_t)k * HID + h * OUT_D;
            a = ((c < 4) ? a_src : a_dst) + h * OUT_D;
        } else {
            int j = wid - IN_DIM * 8;
            int r = j >> 2, h = j & 3;
            row = rel_feat + (size_t)r * HID + h * OUT_D;
            a = a_rel + h * OUT_D;
        }
        float4 wv = *(const float4*)(row + d);
        float4 av = *(const float4*)(a + d);
        acc = wv.x * av.x + wv.y * av.y + wv.z * av.z + wv.w * av.w;
    }
    for (int off = 32; off; off >>= 1) acc += __shfl_down(acc, off, 64);
    if (lane == 0) {
        if (wid < IN_DIM * 8) Wa[wid] = acc;
        else prel[wid - IN_DIM * 8] = acc;
    }
}

// compact score nodes (src_ids ∪ dst_ids) -> slots; record unique score list
__global__ void k_build_slots(const int* src_ids, const int* dst_ids,
                              int* slot_of_node, int* counters, int* scorelist) {
    int i = blockIdx.x * 256 + threadIdx.x;
    if (i >= 2 * BB) return;
    int n = (i < BB) ? src_ids[i] : dst_ids[i - BB];
    if (slot_of_node[n] == -1) {
        if (atomicCAS(&slot_of_node[n], -1, -2) == -1) {
            int s = atomicAdd(&counters[0], 1);
            slot_of_node[n] = s;
            scorelist[s] = n;
        }
    }
}

// survivor pass: compact srcs of surviving edges (xrows 0..nsrc), per-slot degree
__global__ void k_edge0(const int* ei, const int* slot_of_node,
                        int* xrow_of_node, int* counters, int* rows, int* deg) {
    int e = blockIdx.x * 256 + threadIdx.x;
    if (e >= EE) return;
    int dn = ei[EE + e];
    int slot = slot_of_node[dn];
    if (slot < 0) return;
    int sn = ei[e];
    if (xrow_of_node[sn] == -1) {
        if (atomicCAS(&xrow_of_node[sn], -1, -2) == -1) {
            int t = atomicAdd(&counters[1], 1);
            rows[t] = sn;
            xrow_of_node[sn] = t;
        }
    }
    atomicAdd(&deg[slot], 1);
}

// fused: scan (block 0) | tail (blocks 1..64) — both depend only on edge0/build_slots
__global__ __launch_bounds__(256) void k_tail_scan(const int* scorelist, int* xrow_of_node,
                                                   int* counters, int* rows,
                                                   const int* deg, int* base, int* cursor) {
    int t = threadIdx.x;
    if (blockIdx.x == 0) {
        __shared__ int pref[257];
        int s = 0;
        const int4* dv = (const int4*)(deg + t * (SLOT_CAP / 256));
        for (int i = 0; i < SLOT_CAP / 256 / 4; ++i) {
            int4 v = dv[i];
            s += v.x + v.y + v.z + v.w;
        }
        pref[t + 1] = s;
        if (t == 0) pref[0] = 0;
        __syncthreads();
        if (t == 0)
            for (int i = 1; i <= 256; ++i) pref[i] += pref[i - 1];
        __syncthreads();
        int r = pref[t];
        for (int i = 0; i < SLOT_CAP / 256; ++i) {
            int idx = t * (SLOT_CAP / 256) + i;
            base[idx] = r;
            cursor[idx] = r;
            r += deg[idx];
        }
        return;
    }
    int i = (blockIdx.x - 1) * 256 + t;
    if (i >= counters[0]) return;
    int n = scorelist[i];
    if (xrow_of_node[n] < 0) {
        int tt = atomicAdd(&counters[3], 1);
        int xr = counters[1] + tt;   // counters[1] stable: edge0 completed
        xrow_of_node[n] = xr;
        rows[xr] = n;
    }
}

// fused: Wt transpose+cast (blocks 0..223) | gather_cast (blocks 224..)
#define WT_BLOCKS 224   // 16 k-blocks x 14 col-blocks
__global__ __launch_bounds__(256) void k_gather_wt(const float* x, const int* rows,
                                                   const int* counters, unsigned short* xg,
                                                   const float* W, const float* Wa,
                                                   unsigned short* Wt) {
    int t = threadIdx.x;
    if (blockIdx.x < WT_BLOCKS) {
        __shared__ float tile[64][65];
        int b = blockIdx.x;
        int k0 = (b & 15) * 64, c0 = (b >> 4) * 64;
        {
            int kk = t >> 2, cc = (t & 3) * 16;
            for (int i = 0; i < 16; ++i) {
                int c = c0 + cc + i;
                float v = 0.f;
                if (c < HID) v = W[(size_t)(k0 + kk) * HID + c];
                else if (c < HID + 8) v = Wa[(size_t)(k0 + kk) * 8 + (c - HID)];
                tile[cc + i][kk] = v;
            }
        }
        __syncthreads();
        {
            int cc = t >> 2, kk = (t & 3) * 16;
            unsigned short o[16];
            for (int i = 0; i < 16; ++i) o[i] = f2bf(tile[cc][kk + i]);
            *(short8*)(Wt + (size_t)(c0 + cc) * IN_DIM + k0 + kk) = *(short8*)o;
            *(short8*)(Wt + (size_t)(c0 + cc) * IN_DIM + k0 + kk + 8) = *(short8*)(o + 8);
        }
        return;
    }
    int nneed = counters[1] + counters[3];
    int gid = (blockIdx.x - WT_BLOCKS) * 256 + t;
    int row = gid >> 7;            // 128 threads per row, 8 elems each
    if (row >= nneed) return;
    int j = (gid & 127) * 8;
    int node = rows[row];
    const float* src = x + (size_t)node * IN_DIM + j;
    float4 a = *(const float4*)(src);
    float4 b = *(const float4*)(src + 4);
    unsigned short o[8] = {f2bf(a.x), f2bf(a.y), f2bf(a.z), f2bf(a.w),
                           f2bf(b.x), f2bf(b.y), f2bf(b.z), f2bf(b.w)};
    *(short8*)(xg + (size_t)row * IN_DIM + j) = *(short8*)o;
}

// MFMA bf16 GEMM: 128x128 tile (R4 geometry), GBK=64 (two 32-k halves per
// barrier -> 32 MFMA/barrier). global_load_lds(16B), fragment-ordered LDS.
// Col-tiles 0..5: rows < nsrc. Col-tile 6 (768..895): rows < nneed, cols
// 800..807 routed to fp32 sS/sD.
#define GBM 128
#define GBN 128
#define GBK 64
__global__ __launch_bounds__(256) void k_hgemm(const unsigned short* xg, const unsigned short* Wt,
                                               const int* counters, unsigned short* h_src,
                                               float* sS, float* sD) {
    int nsrc = counters[1];
    int nneed = nsrc + counters[3];
    int col0 = blockIdx.x * GBN;
    int row0 = blockIdx.y * GBM;
    int rowlim = (col0 == 768) ? nneed : nsrc;
    if (row0 >= rowlim) return;
    __shared__ unsigned short As[GBM * GBK];  // 16 KB
    __shared__ unsigned short Bs[GBN * GBK];  // 16 KB
    int t = threadIdx.x;
    // chunk c (16B): row (c>>6)*16 + (c&15), k-offset ((c>>4)&3)*8 within a 32-k half
    int crow = ((t >> 6) << 4) + (t & 15), coff = ((t >> 4) & 3) << 3;
    const unsigned short* a0 = xg + (size_t)(row0 + crow) * IN_DIM + coff;
    const unsigned short* a1 = a0 + (size_t)64 * IN_DIM;
    const unsigned short* b0 = Wt + (size_t)(col0 + crow) * IN_DIM + coff;
    const unsigned short* b1 = b0 + (size_t)64 * IN_DIM;
    unsigned short* la0 = As + t * 8;
    unsigned short* la1 = As + (256 + t) * 8;
    unsigned short* la2 = As + (512 + t) * 8;
    unsigned short* la3 = As + (768 + t) * 8;
    unsigned short* lb0 = Bs + t * 8;
    unsigned short* lb1 = Bs + (256 + t) * 8;
    unsigned short* lb2 = Bs + (512 + t) * 8;
    unsigned short* lb3 = Bs + (768 + t) * 8;
    int w = t >> 6, lane = t & 63;
    int ga = (w >> 1) * 4, gb = (w & 1) * 4;
    int wr = (w >> 1) * 64, wc = (w & 1) * 64;
    int fm = lane & 15, fq = lane >> 4;
    f32x4 acc[4][4] = {};
    for (int k0 = 0; k0 < IN_DIM; k0 += GBK) {
        __syncthreads();
        gl2lds16(a0 + k0, la0);
        gl2lds16(a1 + k0, la1);
        gl2lds16(a0 + k0 + 32, la2);
        gl2lds16(a1 + k0 + 32, la3);
        gl2lds16(b0 + k0, lb0);
        gl2lds16(b1 + k0, lb1);
        gl2lds16(b0 + k0 + 32, lb2);
        gl2lds16(b1 + k0 + 32, lb3);
        __syncthreads();
#pragma unroll
        for (int s = 0; s < 2; ++s) {
            short8 af[4], bf[4];
#pragma unroll
            for (int i = 0; i < 4; ++i)
                af[i] = *(const short8*)&As[(s * 512 + (ga + i) * 64 + lane) * 8];
#pragma unroll
            for (int j = 0; j < 4; ++j)
                bf[j] = *(const short8*)&Bs[(s * 512 + (gb + j) * 64 + lane) * 8];
#pragma unroll
            for (int i = 0; i < 4; ++i)
#pragma unroll
                for (int j = 0; j < 4; ++j)
                    acc[i][j] = __builtin_amdgcn_mfma_f32_16x16x32_bf16(af[i], bf[j], acc[i][j], 0, 0, 0);
        }
    }
#pragma unroll
    for (int i = 0; i < 4; ++i) {
#pragma unroll
        for (int j = 0; j < 4; ++j) {
            int gcol = col0 + wc + j * 16 + fm;
            if (gcol >= HID + 8) continue;
#pragma unroll
            for (int r = 0; r < 4; ++r) {
                int grow = row0 + wr + i * 16 + fq * 4 + r;
                float v = acc[i][j][r];
                if (gcol < HID) {
                    if (grow < nsrc) h_src[(size_t)grow * HID + gcol] = f2bf(v);
                } else if (grow < nneed) {
                    int c = gcol - HID;
                    if (c < 4) sS[grow * 4 + c] = v;
                    else sD[grow * 4 + (c - 4)] = v;
                }
            }
        }
    }
}

// place surviving edges into CSR, computing logits at final position
__global__ void k_place(const int* ei, const int* etype, const int* slot_of_node,
                        const int* xrow_of_node, int* cursor,
                        const float* sS, const float* sD, const float* prel,
                        float* clogit, int* tlist) {
    int e = blockIdx.x * 256 + threadIdx.x;
    if (e >= EE) return;
    int dn = ei[EE + e];
    int slot = slot_of_node[dn];
    if (slot < 0) return;
    int sn = ei[e];
    int r = etype[e];
    int xs = xrow_of_node[sn];
    int xd = xrow_of_node[dn];
    int pos = atomicAdd(&cursor[slot], 1);
    tlist[pos] = xs;
    float4 lg;
    float* lp = (float*)&lg;
#pragma unroll
    for (int h = 0; h < 4; ++h) {
        float v = sS[xs * 4 + h] + sD[xd * 4 + h] + prel[r * 4 + h];
        lp[h] = v > 0.f ? v : 0.2f * v;
    }
    *(float4*)&clogit[(size_t)pos * 4] = lg;
}

// per-dst-slot softmax + aggregate (no atomics): one block per slot
__global__ __launch_bounds__(256) void k_aggregate(const int* counters, const int* base,
                                                   const int* deg, const int* tlist,
                                                   const float* clogit,
                                                   const unsigned short* h_src, const float* bias,
                                                   float* refined) {
    int b = blockIdx.x;
    if (b >= counters[0]) return;
    int beg = base[b], d = deg[b];
    __shared__ float m4[4], den4[4];
    __shared__ float alpha[64][4];
    __shared__ int tsl[64];
    int t = threadIdx.x;
    if (t < 4) {
        float m = -3e38f;
        for (int j = 0; j < d; ++j)
            m = fmaxf(m, clogit[(size_t)(beg + j) * 4 + t]);
        float s = 0.f;
        for (int j = 0; j < d; ++j)
            s += expf(clogit[(size_t)(beg + j) * 4 + t] - m);
        m4[t] = m;
        den4[t] = s;
    }
    __syncthreads();
    int h0 = t / 200, h1 = (t + 256) / 200, h2 = (t + 512) / 200;
    float acc0 = 0.f, acc1 = 0.f, acc2 = 0.f, acc3 = 0.f;
    for (int j0 = 0; j0 < d; j0 += 64) {
        int nc = min(64, d - j0);
        if (t < nc * 4) {
            int j = t >> 2, h = t & 3;
            alpha[j][h] = expf(clogit[(size_t)(beg + j0 + j) * 4 + h] - m4[h]) / den4[h];
            if (h == 0) tsl[j] = tlist[beg + j0 + j];
        }
        __syncthreads();
        for (int j = 0; j < nc; ++j) {
            const unsigned short* hr = h_src + (size_t)tsl[j] * HID;
            acc0 += alpha[j][h0] * bf2f(hr[t]);
            acc1 += alpha[j][h1] * bf2f(hr[t + 256]);
            acc2 += alpha[j][h2] * bf2f(hr[t + 512]);
            if (t < 32) acc3 += alpha[j][3] * bf2f(hr[768 + t]);
        }
        __syncthreads();
    }
    float* rr = refined + (size_t)b * HID;
    rr[t] = acc0 + bias[t];
    rr[t + 256] = acc1 + bias[t + 256];
    rr[t + 512] = acc2 + bias[t + 512];
    if (t < 32) rr[768 + t] = acc3 + bias[768 + t];
}

// DistMult scoring: one wave per triple, float4 loads
__global__ __launch_bounds__(256) void k_score(const int* src_ids, const int* rel_ids,
                                               const int* dst_ids, const int* slot_of_node,
                                               const float* rel_emb, const float* refined,
                                               float* out) {
    int gid = blockIdx.x * 256 + threadIdx.x;
    int b = gid >> 6;
    int lane = threadIdx.x & 63;
    if (b >= BB) return;
    int ss = slot_of_node[src_ids[b]];
    int ds = slot_of_node[dst_ids[b]];
    int r = rel_ids[b];
    const float* sv = refined + (size_t)ss * HID;
    const float* dv = refined + (size_t)ds * HID;
    const float* rv = rel_emb + (size_t)r * HID;
    float acc = 0.f;
    for (int c4 = lane; c4 < 200; c4 += 64) {
        float4 s = *(const float4*)(sv + c4 * 4);
        float4 dq = *(const float4*)(dv + c4 * 4);
        float4 rr = *(const float4*)(rv + c4 * 4);
        acc += s.x * rr.x * dq.x + s.y * rr.y * dq.y + s.z * rr.z * dq.z + s.w * rr.w * dq.w;
    }
    for (int off = 32; off; off >>= 1) acc += __shfl_down(acc, off, 64);
    if (lane == 0) out[b] = acc;
}

extern "C" void kernel_launch(void* const* d_in, const int* in_sizes, int n_in,
                              void* d_out, int out_size, void* d_ws, size_t ws_size,
                              hipStream_t stream) {
    const float* node_emb = (const float*)d_in[0];
    const float* W        = (const float*)d_in[1];
    const float* bias     = (const float*)d_in[2];
    const float* a_src    = (const float*)d_in[3];
    const float* a_dst    = (const float*)d_in[4];
    const float* a_rel    = (const float*)d_in[5];
    const float* rel_feat = (const float*)d_in[6];
    const float* rel_emb  = (const float*)d_in[7];
    const int* edge_index = (const int*)d_in[8];
    const int* edge_type  = (const int*)d_in[9];
    const int* src_ids    = (const int*)d_in[10];
    const int* rel_ids    = (const int*)d_in[11];
    const int* dst_ids    = (const int*)d_in[12];
    float* out = (float*)d_out;

    char* w = (char*)d_ws;
    auto alloc = [&](size_t bytes) -> void* {
        void* p = (void*)w;
        w += (bytes + 255) & ~(size_t)255;
        return p;
    };
    int* slot_of_node = (int*)alloc((size_t)NN * 4);
    int* xrow_of_node = (int*)alloc((size_t)NN * 4);
    int* scorelist    = (int*)alloc((size_t)SLOT_CAP * 4);
    int* rows         = (int*)alloc((size_t)NN * 4);
    int* counters     = (int*)alloc(256);
    int* deg          = (int*)alloc((size_t)SLOT_CAP * 4);
    int* base         = (int*)alloc((size_t)SLOT_CAP * 4);
    int* cursor       = (int*)alloc((size_t)SLOT_CAP * 4);
    int* tlist        = (int*)alloc((size_t)EE * 4);
    float* clogit = (float*)alloc((size_t)EE * 4 * 4);
    float* sS     = (float*)alloc((size_t)SRC_CAP * 4 * 4);
    float* sD     = (float*)alloc((size_t)SRC_CAP * 4 * 4);
    float* Wa     = (float*)alloc((size_t)IN_DIM * 8 * 4);
    float* prel   = (float*)alloc((size_t)NUM_REL * 4 * 4);
    unsigned short* xg    = (unsigned short*)alloc((size_t)SRC_CAP * IN_DIM * 2);
    unsigned short* Wt    = (unsigned short*)alloc((size_t)WT_COLS * IN_DIM * 2);
    unsigned short* h_src = (unsigned short*)alloc((size_t)SRC_CAP * HID * 2);
    float* refined = (float*)alloc((size_t)SLOT_CAP * HID * 4);

    int wa_blocks = (IN_DIM * 8 + NUM_REL * HEADS + 3) / 4;
    k_init_wa<<<INIT_BLOCKS + wa_blocks, 256, 0, stream>>>(
        slot_of_node, xrow_of_node, deg, counters,
        W, a_src, a_dst, a_rel, rel_feat, Wa, prel);
    k_build_slots<<<(2 * BB + 255) / 256, 256, 0, stream>>>(src_ids, dst_ids, slot_of_node,
                                                            counters, scorelist);
    k_edge0<<<(EE + 255) / 256, 256, 0, stream>>>(edge_index, slot_of_node,
                                                  xrow_of_node, counters, rows, deg);
    k_tail_scan<<<1 + SLOT_CAP / 256, 256, 0, stream>>>(scorelist, xrow_of_node, counters,
                                                        rows, deg, base, cursor);
    k_gather_wt<<<WT_BLOCKS + (NN * 128) / 256, 256, 0, stream>>>(
        node_emb, rows, counters, xg, W, Wa, Wt);
    dim3 ggrid(WT_COLS / GBN, (SRC_CAP + GBM - 1) / GBM);
    k_hgemm<<<ggrid, 256, 0, stream>>>(xg, Wt, counters, h_src, sS, sD);
    k_place<<<(EE + 255) / 256, 256, 0, stream>>>(edge_index, edge_type, slot_of_node,
                                                  xrow_of_node, cursor, sS, sD, prel,
                                                  clogit, tlist);
    k_aggregate<<<SLOT_CAP, 256, 0, stream>>>(counters, base, deg, tlist,
                                              clogit, h_src, bias, refined);
    k_score<<<(BB * 64 + 255) / 256, 256, 0, stream>>>(src_ids, rel_ids, dst_ids,
                                                       slot_of_node, rel_emb, refined, out);
}